// Round 13
// baseline (225.062 us; speedup 1.0000x reference)
//
#include <hip/hip_runtime.h>
#include <hip/hip_bf16.h>

#define N_NODES 50000
#define MPAD    50048
#define N_EDGES 800000
#define DIM     128
#define N_BATCH 25000
#define NBUCK   196        // ceil(50000/256) buckets of 256 dst nodes
#define BCAP    8192       // per-bucket capacity (mean 4096, sigma 64)
#define NBIN    64         // degree bins for counting sort

typedef unsigned short u16;
typedef unsigned int   u32;
typedef unsigned char  u8;
typedef unsigned long long u64;

typedef __attribute__((ext_vector_type(8))) short bf16x8;
typedef __attribute__((ext_vector_type(4))) float f32x4;
typedef __attribute__((ext_vector_type(2))) float f32x2;

static __device__ __forceinline__ float bf2f(u16 u) {
    union { u32 i; float f; } v; v.i = ((u32)u) << 16; return v.f;
}
static __device__ __forceinline__ u16 f2bf(float f) {
    union { float f; u32 i; } v; v.f = f;
    u32 x = v.i;
    u32 r = x + 0x7fffu + ((x >> 16) & 1u);   // RTNE
    return (u16)(r >> 16);
}
template <bool HI>
static __device__ __forceinline__ u32 pk8(float a, float b, u32 old) {
    return (u32)__builtin_amdgcn_cvt_pk_fp8_f32(a, b, (int)old, HI);
}

// ---- fused setup: edge partition | cast x -> bf16+fp8 | cast W | mark(mult) ----

#define SB_PART 196
#define SB_CX   3324
#define SB_CW   3708
#define SB_MK   3806

__global__ __launch_bounds__(256) void k_setup(
    const int* __restrict__ src, const int* __restrict__ dst,
    int* __restrict__ bcur, u64* __restrict__ ebuf,
    const float* __restrict__ x, u16* __restrict__ xb, u8* __restrict__ x8,
    const float* __restrict__ W1l, const float* __restrict__ W1r,
    const float* __restrict__ W2l, const float* __restrict__ W2r,
    const float* __restrict__ W3l, const float* __restrict__ W3r,
    u16* __restrict__ wout,
    const int* __restrict__ batch, int* __restrict__ mult) {
    __shared__ int hist[NBUCK];
    __shared__ int lbase[NBUCK];
    __shared__ int gdelta[NBUCK];
    __shared__ u64 stage[4096];
    __shared__ int gaddr[4096];
    int bid = blockIdx.x;
    int t = threadIdx.x;

    if (bid < SB_PART) {
        for (int i = t; i < NBUCK; i += 256) hist[i] = 0;
        __syncthreads();

        int base = bid * 4096;
        int cnt = N_EDGES - base; if (cnt > 4096) cnt = 4096; if (cnt < 0) cnt = 0;

        int es[16], ed[16], rr[16];
#pragma unroll
        for (int k = 0; k < 16; ++k) {
            int i = t + (k << 8);
            bool ok = i < cnt;
            int e = ok ? (base + i) : 0;
            int s = src[e], d = dst[e];
            es[k] = s; ed[k] = d;
            int r = -1;
            if (ok) r = atomicAdd(&hist[d >> 8], 1);
            rr[k] = r;
        }
        __syncthreads();

        if (t < 64) {
            int run = 0;
            for (int c = 0; c < 4; ++c) {
                int idx = c * 64 + t;
                int v = (idx < NBUCK) ? hist[idx] : 0;
                int orig = v;
                for (int off = 1; off < 64; off <<= 1) {
                    int u = __shfl_up(v, off);
                    if (t >= off) v += u;
                }
                int tot = __shfl(v, 63);
                if (idx < NBUCK) lbase[idx] = run + v - orig;
                run += tot;
            }
        }
        __syncthreads();

        if (t < NBUCK) {
            int c = hist[t];
            int g = atomicAdd(&bcur[t], c);        // local offset within bucket
            gdelta[t] = t * BCAP + g - lbase[t];   // global delta
        }
        __syncthreads();

#pragma unroll
        for (int k = 0; k < 16; ++k) {
            if (rr[k] >= 0) {
                int b = ed[k] >> 8;
                int slot = lbase[b] + rr[k];
                stage[slot] = (((u64)(u32)ed[k]) << 32) | (u32)es[k];
                gaddr[slot] = gdelta[b] + slot;
            }
        }
        __syncthreads();

        for (int i = t; i < cnt; i += 256) {
            ebuf[gaddr[i]] = stage[i];
        }
    } else if (bid < SB_CX) {
        int gid = (bid - SB_PART) * 256 + t;
        int row = gid >> 4;
        int c8  = (gid & 15) << 3;
        u32 outw[4];
        u32 w0 = 0, w1 = 0;
        if (row < N_NODES) {
            const float4* p = (const float4*)(x + (size_t)row * DIM + c8);
            float4 v0 = p[0], v1 = p[1];
            outw[0] = (u32)f2bf(v0.x) | ((u32)f2bf(v0.y) << 16);
            outw[1] = (u32)f2bf(v0.z) | ((u32)f2bf(v0.w) << 16);
            outw[2] = (u32)f2bf(v1.x) | ((u32)f2bf(v1.y) << 16);
            outw[3] = (u32)f2bf(v1.z) | ((u32)f2bf(v1.w) << 16);
            w0 = pk8<false>(v0.x, v0.y, 0); w0 = pk8<true>(v0.z, v0.w, w0);
            w1 = pk8<false>(v1.x, v1.y, 0); w1 = pk8<true>(v1.z, v1.w, w1);
        } else {
            outw[0] = outw[1] = outw[2] = outw[3] = 0;
        }
        *(uint4*)(xb + (size_t)row * DIM + c8) = *(uint4*)outw;
        uint2 o8; o8.x = w0; o8.y = w1;
        *(uint2*)(x8 + (size_t)row * DIM + c8) = o8;
    } else if (bid < SB_CW) {
        int i = (bid - SB_CX) * 256 + t;
        int mat = i >> 14, off = i & 16383;
        const float* s = (mat == 0) ? W1l : (mat == 1) ? W1r : (mat == 2) ? W2l
                       : (mat == 3) ? W2r : (mat == 4) ? W3l : W3r;
        wout[i] = f2bf(s[off]);
    } else {
        int s = (bid - SB_CW) * 256 + t;
        if (s < N_BATCH) atomicAdd(&mult[batch[s]], 1);
    }
}

// ---- per-bucket: bucket-base scan + degrees + row_ptr + csr + deg hist ----

__global__ __launch_bounds__(256) void k_build(const u64* __restrict__ ebuf,
                                               const int* __restrict__ bcur,
                                               const int* __restrict__ mult,
                                               int* __restrict__ row_ptr,
                                               int* __restrict__ deg,
                                               float* __restrict__ deg_inv,
                                               int* __restrict__ csr_src,
                                               int* __restrict__ c1g,
                                               int* __restrict__ c3g) {
    __shared__ int cnt256[256];
    __shared__ int sh[256];
    __shared__ int cur[256];
    __shared__ int bh1[NBIN];
    __shared__ int bh3[NBIN];
    __shared__ int shbase;
    int b  = blockIdx.x;
    int t  = threadIdx.x;
    int n0 = b << 8;
    cnt256[t] = 0;
    if (t < NBIN) { bh1[t] = 0; bh3[t] = 0; }
    if (t < 64) {
        int s = 0;
        for (int i = t; i < b; i += 64) s += bcur[i];
#pragma unroll
        for (int off = 32; off > 0; off >>= 1) s += __shfl_xor(s, off);
        if (t == 0) shbase = s;
    }
    __syncthreads();
    int bbase = shbase;

    int cnt = bcur[b];
    const u64* eb = ebuf + (size_t)b * BCAP;
    for (int i = t; i < cnt; i += 256) {
        int d = (int)(eb[i] >> 32);
        atomicAdd(&cnt256[d - n0], 1);
    }
    __syncthreads();

    int myc = cnt256[t];
    sh[t] = myc;
    __syncthreads();
    for (int off = 1; off < 256; off <<= 1) {
        int x = (t >= off) ? sh[t - off] : 0;
        __syncthreads();
        sh[t] += x;
        __syncthreads();
    }
    int rp = bbase + sh[t] - myc;
    int n  = n0 + t;
    if (n < N_NODES) {
        row_ptr[n] = rp;
        deg[n]     = myc;
        deg_inv[n] = 1.0f / (float)(myc < 1 ? 1 : myc);
        int bin = myc < NBIN ? myc : NBIN - 1;
        atomicAdd(&bh1[bin], 1);
        if (mult[n]) atomicAdd(&bh3[bin], 1);
    }
    cur[t] = rp;
    __syncthreads();

    for (int i = t; i < cnt; i += 256) {
        u64 p = eb[i];
        int d = (int)(p >> 32);
        int s = (int)(u32)p;
        int pos = atomicAdd(&cur[d - n0], 1);
        csr_src[pos] = s;
    }
    __syncthreads();
    if (t < NBIN) {
        if (bh1[t]) atomicAdd(&c1g[t], bh1[t]);
        if (bh3[t]) atomicAdd(&c3g[t], bh3[t]);
    }
}

// ---- counting-sort scatter (self-scanning): nodes into degree-sorted worklists ----

__global__ __launch_bounds__(256) void k_dscatter(const int* __restrict__ deg,
                                                  const int* __restrict__ mult,
                                                  const int* __restrict__ c1g,
                                                  const int* __restrict__ c3g,
                                                  int* __restrict__ o1g,
                                                  int* __restrict__ o3g,
                                                  int* __restrict__ wl1,
                                                  int* __restrict__ wl3,
                                                  int* __restrict__ n3) {
    __shared__ int bh1[NBIN], bh3[NBIN], bb1[NBIN], bb3[NBIN];
    int t = threadIdx.x;
    int n = blockIdx.x * 256 + t;
    if (t < NBIN) { bh1[t] = 0; bh3[t] = 0; }
    __syncthreads();
    bool valid = n < N_NODES;
    int d = 0, r1 = -1, r3 = -1;
    if (valid) {
        d = deg[n]; if (d >= NBIN) d = NBIN - 1;
        r1 = atomicAdd(&bh1[d], 1);
        if (mult[n]) r3 = atomicAdd(&bh3[d], 1);
    }
    __syncthreads();
    if (t < 64) {
        int v1 = c1g[t], v3 = c3g[t];
        int i1 = v1, i3 = v3;
        for (int off = 1; off < 64; off <<= 1) {
            int u1 = __shfl_up(i1, off);
            int u3 = __shfl_up(i3, off);
            if (t >= off) { i1 += u1; i3 += u3; }
        }
        int res1 = atomicAdd(&o1g[t], bh1[t]);
        int res3 = atomicAdd(&o3g[t], bh3[t]);
        bb1[t] = (i1 - v1) + res1;
        bb3[t] = (i3 - v3) + res3;
        if (blockIdx.x == 0 && t == 63) n3[0] = i3;
    }
    __syncthreads();
    if (valid) {
        wl1[bb1[d] + r1] = n;
        if (r3 >= 0) wl3[bb3[d] + r3] = n;
    }
}

// ---- fused SAGE layer (R9 structure + upfront index prefetch) ----
// 16 lanes/node, 4 nodes/wave, 16 nodes/block. Index batches for deg<=64
// loaded upfront (independent latency), gathers 8-deep.

template <bool RELU, bool PRUNED, bool W8>
__global__ __launch_bounds__(256) void k_sage(
    const u16* __restrict__ h, const u8* __restrict__ h8,
    const int* __restrict__ csr_src,
    const int* __restrict__ row_ptr, const int* __restrict__ deg,
    const float* __restrict__ deg_inv,
    const int* __restrict__ wl, const int* __restrict__ wlN,
    const u16* __restrict__ Wl, const u16* __restrict__ Wr,
    const float* __restrict__ bias, u16* __restrict__ out,
    u8* __restrict__ out8) {
    __shared__ u16 tile[16 * 128];
    __shared__ int wlid[16];
    int nwl = PRUNED ? wlN[0] : N_NODES;
    int m0  = blockIdx.x * 16;
    if (m0 >= nwl) return;

    int t    = threadIdx.x;
    int lane = t & 63;
    int wid  = t >> 6;
    int sub  = lane & 15;
    int grp  = lane >> 4;
    int nloc = (wid << 2) + grp;
    int gb   = lane & 48;
    int node = (m0 + nloc < nwl) ? wl[m0 + nloc] : -1;
    if (sub == 0) wlid[nloc] = node;

    float a0 = 0, a1 = 0, a2 = 0, a3 = 0, a4 = 0, a5 = 0, a6 = 0, a7 = 0;

#define ACC8(r) { f32x2 p; \
    p = __builtin_amdgcn_cvt_pk_f32_fp8((r).x, false); a0 += p[0]; a1 += p[1]; \
    p = __builtin_amdgcn_cvt_pk_f32_fp8((r).x, true);  a2 += p[0]; a3 += p[1]; \
    p = __builtin_amdgcn_cvt_pk_f32_fp8((r).y, false); a4 += p[0]; a5 += p[1]; \
    p = __builtin_amdgcn_cvt_pk_f32_fp8((r).y, true);  a6 += p[0]; a7 += p[1]; }

    if (node >= 0) {
        int start = row_ptr[node];
        int cnt   = deg[node];

        // upfront independent index loads: cover deg <= 64 (4 batches of 16)
        int sidx0 = 0, sidx1 = 0, sidx2 = 0, sidx3 = 0;
        if (sub < cnt)      sidx0 = csr_src[start + sub];
        if (16 + sub < cnt) sidx1 = csr_src[start + 16 + sub];
        if (32 + sub < cnt) sidx2 = csr_src[start + 32 + sub];
        if (48 + sub < cnt) sidx3 = csr_src[start + 48 + sub];

        auto process = [&](int sidx, int rem) {
            int j = 0;
            for (; j + 8 <= rem; j += 8) {
                int i0 = __shfl(sidx, gb + j);
                int i1 = __shfl(sidx, gb + j + 1);
                int i2 = __shfl(sidx, gb + j + 2);
                int i3 = __shfl(sidx, gb + j + 3);
                int i4 = __shfl(sidx, gb + j + 4);
                int i5 = __shfl(sidx, gb + j + 5);
                int i6 = __shfl(sidx, gb + j + 6);
                int i7 = __shfl(sidx, gb + j + 7);
                uint2 r0 = *(const uint2*)(h8 + (size_t)i0 * DIM + sub * 8);
                uint2 r1 = *(const uint2*)(h8 + (size_t)i1 * DIM + sub * 8);
                uint2 r2 = *(const uint2*)(h8 + (size_t)i2 * DIM + sub * 8);
                uint2 r3 = *(const uint2*)(h8 + (size_t)i3 * DIM + sub * 8);
                uint2 r4 = *(const uint2*)(h8 + (size_t)i4 * DIM + sub * 8);
                uint2 r5 = *(const uint2*)(h8 + (size_t)i5 * DIM + sub * 8);
                uint2 r6 = *(const uint2*)(h8 + (size_t)i6 * DIM + sub * 8);
                uint2 r7 = *(const uint2*)(h8 + (size_t)i7 * DIM + sub * 8);
                ACC8(r0); ACC8(r1); ACC8(r2); ACC8(r3);
                ACC8(r4); ACC8(r5); ACC8(r6); ACC8(r7);
            }
            for (; j + 4 <= rem; j += 4) {
                int i0 = __shfl(sidx, gb + j);
                int i1 = __shfl(sidx, gb + j + 1);
                int i2 = __shfl(sidx, gb + j + 2);
                int i3 = __shfl(sidx, gb + j + 3);
                uint2 r0 = *(const uint2*)(h8 + (size_t)i0 * DIM + sub * 8);
                uint2 r1 = *(const uint2*)(h8 + (size_t)i1 * DIM + sub * 8);
                uint2 r2 = *(const uint2*)(h8 + (size_t)i2 * DIM + sub * 8);
                uint2 r3 = *(const uint2*)(h8 + (size_t)i3 * DIM + sub * 8);
                ACC8(r0); ACC8(r1); ACC8(r2); ACC8(r3);
            }
            for (; j < rem; ++j) {
                int i0 = __shfl(sidx, gb + j);
                uint2 r0 = *(const uint2*)(h8 + (size_t)i0 * DIM + sub * 8);
                ACC8(r0);
            }
        };

        int rem0 = cnt < 16 ? cnt : 16;
        process(sidx0, rem0);
        if (cnt > 16) process(sidx1, (cnt - 16) < 16 ? (cnt - 16) : 16);
        if (cnt > 32) process(sidx2, (cnt - 32) < 16 ? (cnt - 32) : 16);
        if (cnt > 48) process(sidx3, (cnt - 48) < 16 ? (cnt - 48) : 16);
        for (int c0 = 64; c0 < cnt; c0 += 16) {     // rare tail (deg > 64)
            int rem = cnt - c0; if (rem > 16) rem = 16;
            int sidx = 0;
            if (sub < rem) sidx = csr_src[start + c0 + sub];
            process(sidx, rem);
        }

        float inv = deg_inv[node];
        a0 *= inv; a1 *= inv; a2 *= inv; a3 *= inv;
        a4 *= inv; a5 *= inv; a6 *= inv; a7 *= inv;
    }
#undef ACC8

    // pack mean row into swizzled LDS tile
    {
        uint4 o;
        o.x = (u32)f2bf(a0) | ((u32)f2bf(a1) << 16);
        o.y = (u32)f2bf(a2) | ((u32)f2bf(a3) << 16);
        o.z = (u32)f2bf(a4) | ((u32)f2bf(a5) << 16);
        o.w = (u32)f2bf(a6) | ((u32)f2bf(a7) << 16);
        int chunk = sub ^ (nloc & 7);
        *(uint4*)&tile[nloc * 128 + chunk * 8] = o;
    }
    __syncthreads();

    // MFMA phase
    const int fr = sub;
    const int kq = grp << 3;
    bf16x8 aF0[4], aF1[4];
    int rnode = wlid[fr];
    int safe_r = rnode < 0 ? 0 : rnode;
    const u16* ph = h + (size_t)safe_r * DIM + kq;
#pragma unroll
    for (int kt = 0; kt < 4; ++kt) {
        int c = (grp + kt * 4) ^ (fr & 7);
        aF0[kt] = *(const bf16x8*)&tile[fr * 128 + c * 8];
        aF1[kt] = *(const bf16x8*)(ph + kt * 32);
    }
#pragma unroll
    for (int q = 0; q < 2; ++q) {
        int nt = wid * 2 + q;
        const u16* pwl = Wl + (size_t)(nt * 16 + fr) * DIM + kq;
        const u16* pwr = Wr + (size_t)(nt * 16 + fr) * DIM + kq;
        f32x4 acc = {0.f, 0.f, 0.f, 0.f};
#pragma unroll
        for (int kt = 0; kt < 4; ++kt) {
            bf16x8 w = *(const bf16x8*)(pwl + kt * 32);
            acc = __builtin_amdgcn_mfma_f32_16x16x32_bf16(aF0[kt], w, acc, 0, 0, 0);
        }
#pragma unroll
        for (int kt = 0; kt < 4; ++kt) {
            bf16x8 w = *(const bf16x8*)(pwr + kt * 32);
            acc = __builtin_amdgcn_mfma_f32_16x16x32_bf16(aF1[kt], w, acc, 0, 0, 0);
        }
        int col = nt * 16 + fr;
        float b = bias[col];
#pragma unroll
        for (int j = 0; j < 4; ++j) {
            int onode = wlid[(grp << 2) + j];
            if (onode >= 0) {
                float v = acc[j] + b;
                if (RELU) v = fmaxf(v, 0.f);
                out[(size_t)onode * DIM + col] = f2bf(v);
                if (W8) out8[(size_t)onode * DIM + col] = (u8)(pk8<false>(v, v, 0) & 0xffu);
            }
        }
    }
}

// ---------------- head: softmax -> log_softmax -> NLL mean (+finalize) ----------------

__global__ __launch_bounds__(256) void k_head(
    const u16* __restrict__ h3, const int* __restrict__ batch,
    const int* __restrict__ labels, const float* __restrict__ Wlin,
    const float* __restrict__ blin, float* __restrict__ accum,
    int* __restrict__ hcount, float* __restrict__ out) {
    __shared__ float wsh[256];
    __shared__ float red[4];
    int t = threadIdx.x;
    wsh[t] = Wlin[t];
    __syncthreads();

    int lane = t & 63;
    int g    = lane >> 4;
    int sub  = lane & 15;
    int wv   = (blockIdx.x * 256 + t) >> 6;
    int samp = wv * 4 + g;

    float contrib = 0.f;
    float z0 = 0.f, z1 = 0.f;
    int n = 0;
    if (samp < N_BATCH) {
        n = batch[samp];
        uint4 u = *(const uint4*)(h3 + (size_t)n * DIM + sub * 8);
        const u32* uw = (const u32*)&u;
        int cb = sub * 8;
#pragma unroll
        for (int q = 0; q < 4; ++q) {
            float hlo = bf2f((u16)(uw[q] & 0xffffu));
            float hhi = bf2f((u16)(uw[q] >> 16));
            z0 += hlo * wsh[cb + q * 2]       + hhi * wsh[cb + q * 2 + 1];
            z1 += hlo * wsh[128 + cb + q * 2] + hhi * wsh[128 + cb + q * 2 + 1];
        }
    }
#pragma unroll
    for (int off = 8; off > 0; off >>= 1) {
        z0 += __shfl_xor(z0, off);
        z1 += __shfl_xor(z1, off);
    }
    if (samp < N_BATCH) {
        z0 += blin[0]; z1 += blin[1];
        float m  = fmaxf(z0, z1);
        float e0 = expf(z0 - m), e1 = expf(z1 - m);
        float s  = e0 + e1;
        float p0 = e0 / s, p1 = e1 / s;
        float m2  = fmaxf(p0, p1);
        float lse = m2 + logf(expf(p0 - m2) + expf(p1 - m2));
        int lab = labels[n];
        float lp = ((lab == 0) ? p0 : p1) - lse;
        if (sub == 0) contrib = -lp * (1.0f / (float)N_BATCH);
    }
#pragma unroll
    for (int off = 16; off < 64; off <<= 1) contrib += __shfl_xor(contrib, off);
    if (lane == 0) red[t >> 6] = contrib;
    __syncthreads();
    if (t == 0) {
        atomicAdd(accum, red[0] + red[1] + red[2] + red[3]);
        __threadfence();
        int c = atomicAdd(hcount, 1);
        if (c == (int)gridDim.x - 1) {
            float v = atomicAdd(accum, 0.0f);
            out[0] = v;
        }
    }
}

// ---------------- launch ----------------

extern "C" void kernel_launch(void* const* d_in, const int* in_sizes, int n_in,
                              void* d_out, int out_size, void* d_ws, size_t ws_size,
                              hipStream_t stream) {
    const float* x    = (const float*)d_in[0];
    const int*   eidx = (const int*)d_in[1];
    const int*   batch  = (const int*)d_in[2];
    const int*   labels = (const int*)d_in[3];
    const float* W1l = (const float*)d_in[4];
    const float* b1  = (const float*)d_in[5];
    const float* W1r = (const float*)d_in[6];
    const float* W2l = (const float*)d_in[7];
    const float* b2  = (const float*)d_in[8];
    const float* W2r = (const float*)d_in[9];
    const float* W3l = (const float*)d_in[10];
    const float* b3  = (const float*)d_in[11];
    const float* W3r = (const float*)d_in[12];
    const float* Wlin = (const float*)d_in[13];
    const float* blin = (const float*)d_in[14];

    const int* src = eidx;
    const int* dst = eidx + N_EDGES;

    size_t off = 0;
    auto alloc = [&](size_t bytes) -> char* {
        off = (off + 511) & ~(size_t)511;
        char* p = (char*)d_ws + off;
        off += bytes;
        return p;
    };
    // ---- contiguous zero-init region (one hipMemsetAsync) ----
    size_t zbytes = (size_t)MPAD * 4 + NBUCK * 4 + 4 * NBIN * 4 + 8;
    char* zbase = alloc(zbytes);
    int*   mult   = (int*)zbase;
    int*   bcur   = mult + MPAD;
    int*   c1g    = bcur + NBUCK;
    int*   c3g    = c1g + NBIN;
    int*   o1g    = c3g + NBIN;
    int*   o3g    = o1g + NBIN;
    float* accum  = (float*)(o3g + NBIN);
    int*   hcount = (int*)(accum + 1);

    int*   row_ptr = (int*)  alloc(N_NODES * 4);
    int*   deg     = (int*)  alloc(N_NODES * 4);
    float* deg_inv = (float*)alloc(N_NODES * 4);
    int*   csr_src = (int*)  alloc(N_EDGES * 4);
    u64*   ebuf    = (u64*)  alloc((size_t)NBUCK * BCAP * 8);
    u16*   wb      = (u16*)  alloc(6 * DIM * DIM * 2);
    u16*   xb      = (u16*)  alloc((size_t)MPAD * DIM * 2);   // reused as bufB
    u16*   bufA    = (u16*)  alloc((size_t)MPAD * DIM * 2);
    u8*    x8      = (u8*)   alloc((size_t)MPAD * DIM);
    u8*    a8      = (u8*)   alloc((size_t)MPAD * DIM);
    u8*    b8      = (u8*)   alloc((size_t)MPAD * DIM);
    int*   wl1     = (int*)  alloc(MPAD * 4);
    int*   wl3     = (int*)  alloc(MPAD * 4);
    int*   n3      = (int*)  alloc(4);

    u16* bufB = xb;

    u16* w1l = wb + 0 * DIM * DIM;
    u16* w1r = wb + 1 * DIM * DIM;
    u16* w2l = wb + 2 * DIM * DIM;
    u16* w2r = wb + 3 * DIM * DIM;
    u16* w3l = wb + 4 * DIM * DIM;
    u16* w3r = wb + 5 * DIM * DIM;

    const int NB196 = (N_NODES + 255) / 256;      // 196
    const int SGB   = N_NODES / 16;               // 3125
    const int HB2   = (N_BATCH + 15) / 16;        // 1563

    hipMemsetAsync(zbase, 0, zbytes, stream);
    k_setup<<<SB_MK, 256, 0, stream>>>(src, dst, bcur, ebuf,
                                       x, xb, x8,
                                       W1l, W1r, W2l, W2r, W3l, W3r, wb,
                                       batch, mult);
    k_build<<<NBUCK, 256, 0, stream>>>(ebuf, bcur, mult, row_ptr, deg,
                                       deg_inv, csr_src, c1g, c3g);
    k_dscatter<<<NB196, 256, 0, stream>>>(deg, mult, c1g, c3g, o1g, o3g,
                                          wl1, wl3, n3);

    k_sage<true, false, true><<<SGB, 256, 0, stream>>>(
        xb, x8, csr_src, row_ptr, deg, deg_inv, wl1, n3, w1l, w1r, b1, bufA, a8);
    k_sage<true, false, true><<<SGB, 256, 0, stream>>>(
        bufA, a8, csr_src, row_ptr, deg, deg_inv, wl1, n3, w2l, w2r, b2, bufB, b8);
    k_sage<false, true, false><<<SGB, 256, 0, stream>>>(
        bufB, b8, csr_src, row_ptr, deg, deg_inv, wl3, n3, w3l, w3r, b3, bufA, nullptr);

    k_head<<<HB2, 256, 0, stream>>>(bufA, batch, labels, Wlin, blin,
                                    accum, hcount, (float*)d_out);
}

// Round 14
// 208.584 us; speedup vs baseline: 1.0790x; 1.0790x over previous
//
#include <hip/hip_runtime.h>
#include <hip/hip_bf16.h>

#define N_NODES 50000
#define MPAD    50048
#define N_EDGES 800000
#define DIM     128
#define N_BATCH 25000
#define NBUCK   196        // ceil(50000/256) buckets of 256 dst nodes
#define BCAP    8192       // per-bucket capacity (mean 4096, sigma 64)
#define NBIN    64         // degree bins for counting sort

typedef unsigned short u16;
typedef unsigned int   u32;
typedef unsigned char  u8;
typedef unsigned long long u64;

typedef __attribute__((ext_vector_type(8))) short bf16x8;
typedef __attribute__((ext_vector_type(4))) float f32x4;
typedef __attribute__((ext_vector_type(2))) float f32x2;

static __device__ __forceinline__ float bf2f(u16 u) {
    union { u32 i; float f; } v; v.i = ((u32)u) << 16; return v.f;
}
static __device__ __forceinline__ u16 f2bf(float f) {
    union { float f; u32 i; } v; v.f = f;
    u32 x = v.i;
    u32 r = x + 0x7fffu + ((x >> 16) & 1u);   // RTNE
    return (u16)(r >> 16);
}
template <bool HI>
static __device__ __forceinline__ u32 pk8(float a, float b, u32 old) {
    return (u32)__builtin_amdgcn_cvt_pk_fp8_f32(a, b, (int)old, HI);
}

// ---- fused setup: edge partition | cast x -> bf16+fp8 | cast W | mark(mult) ----

#define SB_PART 196
#define SB_CX   3324
#define SB_CW   3708
#define SB_MK   3806

__global__ __launch_bounds__(256) void k_setup(
    const int* __restrict__ src, const int* __restrict__ dst,
    int* __restrict__ bcur, u64* __restrict__ ebuf,
    const float* __restrict__ x, u16* __restrict__ xb, u8* __restrict__ x8,
    const float* __restrict__ W1l, const float* __restrict__ W1r,
    const float* __restrict__ W2l, const float* __restrict__ W2r,
    const float* __restrict__ W3l, const float* __restrict__ W3r,
    u16* __restrict__ wout,
    const int* __restrict__ batch, int* __restrict__ mult) {
    __shared__ int hist[NBUCK];
    __shared__ int lbase[NBUCK];
    __shared__ int gdelta[NBUCK];
    __shared__ u64 stage[4096];
    __shared__ int gaddr[4096];
    int bid = blockIdx.x;
    int t = threadIdx.x;

    if (bid < SB_PART) {
        for (int i = t; i < NBUCK; i += 256) hist[i] = 0;
        __syncthreads();

        int base = bid * 4096;
        int cnt = N_EDGES - base; if (cnt > 4096) cnt = 4096; if (cnt < 0) cnt = 0;

        int es[16], ed[16], rr[16];
#pragma unroll
        for (int k = 0; k < 16; ++k) {
            int i = t + (k << 8);
            bool ok = i < cnt;
            int e = ok ? (base + i) : 0;
            int s = src[e], d = dst[e];
            es[k] = s; ed[k] = d;
            int r = -1;
            if (ok) r = atomicAdd(&hist[d >> 8], 1);
            rr[k] = r;
        }
        __syncthreads();

        if (t < 64) {
            int run = 0;
            for (int c = 0; c < 4; ++c) {
                int idx = c * 64 + t;
                int v = (idx < NBUCK) ? hist[idx] : 0;
                int orig = v;
                for (int off = 1; off < 64; off <<= 1) {
                    int u = __shfl_up(v, off);
                    if (t >= off) v += u;
                }
                int tot = __shfl(v, 63);
                if (idx < NBUCK) lbase[idx] = run + v - orig;
                run += tot;
            }
        }
        __syncthreads();

        if (t < NBUCK) {
            int c = hist[t];
            int g = atomicAdd(&bcur[t], c);        // local offset within bucket
            gdelta[t] = t * BCAP + g - lbase[t];   // global delta
        }
        __syncthreads();

#pragma unroll
        for (int k = 0; k < 16; ++k) {
            if (rr[k] >= 0) {
                int b = ed[k] >> 8;
                int slot = lbase[b] + rr[k];
                stage[slot] = (((u64)(u32)ed[k]) << 32) | (u32)es[k];
                gaddr[slot] = gdelta[b] + slot;
            }
        }
        __syncthreads();

        for (int i = t; i < cnt; i += 256) {
            ebuf[gaddr[i]] = stage[i];
        }
    } else if (bid < SB_CX) {
        int gid = (bid - SB_PART) * 256 + t;
        int row = gid >> 4;
        int c8  = (gid & 15) << 3;
        u32 outw[4];
        u32 w0 = 0, w1 = 0;
        if (row < N_NODES) {
            const float4* p = (const float4*)(x + (size_t)row * DIM + c8);
            float4 v0 = p[0], v1 = p[1];
            outw[0] = (u32)f2bf(v0.x) | ((u32)f2bf(v0.y) << 16);
            outw[1] = (u32)f2bf(v0.z) | ((u32)f2bf(v0.w) << 16);
            outw[2] = (u32)f2bf(v1.x) | ((u32)f2bf(v1.y) << 16);
            outw[3] = (u32)f2bf(v1.z) | ((u32)f2bf(v1.w) << 16);
            w0 = pk8<false>(v0.x, v0.y, 0); w0 = pk8<true>(v0.z, v0.w, w0);
            w1 = pk8<false>(v1.x, v1.y, 0); w1 = pk8<true>(v1.z, v1.w, w1);
        } else {
            outw[0] = outw[1] = outw[2] = outw[3] = 0;
        }
        *(uint4*)(xb + (size_t)row * DIM + c8) = *(uint4*)outw;
        uint2 o8; o8.x = w0; o8.y = w1;
        *(uint2*)(x8 + (size_t)row * DIM + c8) = o8;
    } else if (bid < SB_CW) {
        int i = (bid - SB_CX) * 256 + t;
        int mat = i >> 14, off = i & 16383;
        const float* s = (mat == 0) ? W1l : (mat == 1) ? W1r : (mat == 2) ? W2l
                       : (mat == 3) ? W2r : (mat == 4) ? W3l : W3r;
        wout[i] = f2bf(s[off]);
    } else {
        int s = (bid - SB_CW) * 256 + t;
        if (s < N_BATCH) atomicAdd(&mult[batch[s]], 1);
    }
}

// ---- per-bucket: bucket-base scan + degrees + row_ptr + csr + deg hist ----

__global__ __launch_bounds__(256) void k_build(const u64* __restrict__ ebuf,
                                               const int* __restrict__ bcur,
                                               const int* __restrict__ mult,
                                               int* __restrict__ row_ptr,
                                               int* __restrict__ deg,
                                               float* __restrict__ deg_inv,
                                               int* __restrict__ csr_src,
                                               int* __restrict__ c1g,
                                               int* __restrict__ c3g) {
    __shared__ int cnt256[256];
    __shared__ int sh[256];
    __shared__ int cur[256];
    __shared__ int bh1[NBIN];
    __shared__ int bh3[NBIN];
    __shared__ int shbase;
    int b  = blockIdx.x;
    int t  = threadIdx.x;
    int n0 = b << 8;
    cnt256[t] = 0;
    if (t < NBIN) { bh1[t] = 0; bh3[t] = 0; }
    if (t < 64) {
        int s = 0;
        for (int i = t; i < b; i += 64) s += bcur[i];
#pragma unroll
        for (int off = 32; off > 0; off >>= 1) s += __shfl_xor(s, off);
        if (t == 0) shbase = s;
    }
    __syncthreads();
    int bbase = shbase;

    int cnt = bcur[b];
    const u64* eb = ebuf + (size_t)b * BCAP;
    for (int i = t; i < cnt; i += 256) {
        int d = (int)(eb[i] >> 32);
        atomicAdd(&cnt256[d - n0], 1);
    }
    __syncthreads();

    int myc = cnt256[t];
    sh[t] = myc;
    __syncthreads();
    for (int off = 1; off < 256; off <<= 1) {
        int x = (t >= off) ? sh[t - off] : 0;
        __syncthreads();
        sh[t] += x;
        __syncthreads();
    }
    int rp = bbase + sh[t] - myc;
    int n  = n0 + t;
    if (n < N_NODES) {
        row_ptr[n] = rp;
        deg[n]     = myc;
        deg_inv[n] = 1.0f / (float)(myc < 1 ? 1 : myc);
        int bin = myc < NBIN ? myc : NBIN - 1;
        atomicAdd(&bh1[bin], 1);
        if (mult[n]) atomicAdd(&bh3[bin], 1);
    }
    cur[t] = rp;
    __syncthreads();

    for (int i = t; i < cnt; i += 256) {
        u64 p = eb[i];
        int d = (int)(p >> 32);
        int s = (int)(u32)p;
        int pos = atomicAdd(&cur[d - n0], 1);
        csr_src[pos] = s;
    }
    __syncthreads();
    if (t < NBIN) {
        if (bh1[t]) atomicAdd(&c1g[t], bh1[t]);
        if (bh3[t]) atomicAdd(&c3g[t], bh3[t]);
    }
}

// ---- counting-sort scatter (self-scanning): nodes into degree-sorted worklists ----

__global__ __launch_bounds__(256) void k_dscatter(const int* __restrict__ deg,
                                                  const int* __restrict__ mult,
                                                  const int* __restrict__ c1g,
                                                  const int* __restrict__ c3g,
                                                  int* __restrict__ o1g,
                                                  int* __restrict__ o3g,
                                                  int* __restrict__ wl1,
                                                  int* __restrict__ wl3,
                                                  int* __restrict__ n3) {
    __shared__ int bh1[NBIN], bh3[NBIN], bb1[NBIN], bb3[NBIN];
    int t = threadIdx.x;
    int n = blockIdx.x * 256 + t;
    if (t < NBIN) { bh1[t] = 0; bh3[t] = 0; }
    __syncthreads();
    bool valid = n < N_NODES;
    int d = 0, r1 = -1, r3 = -1;
    if (valid) {
        d = deg[n]; if (d >= NBIN) d = NBIN - 1;
        r1 = atomicAdd(&bh1[d], 1);
        if (mult[n]) r3 = atomicAdd(&bh3[d], 1);
    }
    __syncthreads();
    if (t < 64) {
        int v1 = c1g[t], v3 = c3g[t];
        int i1 = v1, i3 = v3;
        for (int off = 1; off < 64; off <<= 1) {
            int u1 = __shfl_up(i1, off);
            int u3 = __shfl_up(i3, off);
            if (t >= off) { i1 += u1; i3 += u3; }
        }
        int res1 = atomicAdd(&o1g[t], bh1[t]);
        int res3 = atomicAdd(&o3g[t], bh3[t]);
        bb1[t] = (i1 - v1) + res1;
        bb3[t] = (i3 - v3) + res3;
        if (blockIdx.x == 0 && t == 63) n3[0] = i3;
    }
    __syncthreads();
    if (valid) {
        wl1[bb1[d] + r1] = n;
        if (r3 >= 0) wl3[bb3[d] + r3] = n;
    }
}

// ---- fused SAGE layer (exact R9 structure): fp8 gather -> mean -> LDS -> MFMA ----
// 16 lanes/node, 4 nodes/wave, 16 nodes/block, uint2 gathers 8-deep.

template <bool RELU, bool PRUNED, bool W8>
__global__ __launch_bounds__(256) void k_sage(
    const u16* __restrict__ h, const u8* __restrict__ h8,
    const int* __restrict__ csr_src,
    const int* __restrict__ row_ptr, const int* __restrict__ deg,
    const float* __restrict__ deg_inv,
    const int* __restrict__ wl, const int* __restrict__ wlN,
    const u16* __restrict__ Wl, const u16* __restrict__ Wr,
    const float* __restrict__ bias, u16* __restrict__ out,
    u8* __restrict__ out8) {
    __shared__ u16 tile[16 * 128];
    __shared__ int wlid[16];
    int nwl = PRUNED ? wlN[0] : N_NODES;
    int m0  = blockIdx.x * 16;
    if (m0 >= nwl) return;

    int t    = threadIdx.x;
    int lane = t & 63;
    int wid  = t >> 6;
    int sub  = lane & 15;
    int grp  = lane >> 4;
    int nloc = (wid << 2) + grp;
    int gb   = lane & 48;
    int node = (m0 + nloc < nwl) ? wl[m0 + nloc] : -1;
    if (sub == 0) wlid[nloc] = node;

    float a0 = 0, a1 = 0, a2 = 0, a3 = 0, a4 = 0, a5 = 0, a6 = 0, a7 = 0;

#define ACC8(r) { f32x2 p; \
    p = __builtin_amdgcn_cvt_pk_f32_fp8((r).x, false); a0 += p[0]; a1 += p[1]; \
    p = __builtin_amdgcn_cvt_pk_f32_fp8((r).x, true);  a2 += p[0]; a3 += p[1]; \
    p = __builtin_amdgcn_cvt_pk_f32_fp8((r).y, false); a4 += p[0]; a5 += p[1]; \
    p = __builtin_amdgcn_cvt_pk_f32_fp8((r).y, true);  a6 += p[0]; a7 += p[1]; }

    if (node >= 0) {
        int start = row_ptr[node];
        int cnt   = deg[node];
        for (int c0 = 0; c0 < cnt; c0 += 16) {
            int rem = cnt - c0; if (rem > 16) rem = 16;
            int sidx = 0;
            if (sub < rem) sidx = csr_src[start + c0 + sub];
            int j = 0;
            for (; j + 8 <= rem; j += 8) {
                int i0 = __shfl(sidx, gb + j);
                int i1 = __shfl(sidx, gb + j + 1);
                int i2 = __shfl(sidx, gb + j + 2);
                int i3 = __shfl(sidx, gb + j + 3);
                int i4 = __shfl(sidx, gb + j + 4);
                int i5 = __shfl(sidx, gb + j + 5);
                int i6 = __shfl(sidx, gb + j + 6);
                int i7 = __shfl(sidx, gb + j + 7);
                uint2 r0 = *(const uint2*)(h8 + (size_t)i0 * DIM + sub * 8);
                uint2 r1 = *(const uint2*)(h8 + (size_t)i1 * DIM + sub * 8);
                uint2 r2 = *(const uint2*)(h8 + (size_t)i2 * DIM + sub * 8);
                uint2 r3 = *(const uint2*)(h8 + (size_t)i3 * DIM + sub * 8);
                uint2 r4 = *(const uint2*)(h8 + (size_t)i4 * DIM + sub * 8);
                uint2 r5 = *(const uint2*)(h8 + (size_t)i5 * DIM + sub * 8);
                uint2 r6 = *(const uint2*)(h8 + (size_t)i6 * DIM + sub * 8);
                uint2 r7 = *(const uint2*)(h8 + (size_t)i7 * DIM + sub * 8);
                ACC8(r0); ACC8(r1); ACC8(r2); ACC8(r3);
                ACC8(r4); ACC8(r5); ACC8(r6); ACC8(r7);
            }
            for (; j + 4 <= rem; j += 4) {
                int i0 = __shfl(sidx, gb + j);
                int i1 = __shfl(sidx, gb + j + 1);
                int i2 = __shfl(sidx, gb + j + 2);
                int i3 = __shfl(sidx, gb + j + 3);
                uint2 r0 = *(const uint2*)(h8 + (size_t)i0 * DIM + sub * 8);
                uint2 r1 = *(const uint2*)(h8 + (size_t)i1 * DIM + sub * 8);
                uint2 r2 = *(const uint2*)(h8 + (size_t)i2 * DIM + sub * 8);
                uint2 r3 = *(const uint2*)(h8 + (size_t)i3 * DIM + sub * 8);
                ACC8(r0); ACC8(r1); ACC8(r2); ACC8(r3);
            }
            for (; j < rem; ++j) {
                int i0 = __shfl(sidx, gb + j);
                uint2 r0 = *(const uint2*)(h8 + (size_t)i0 * DIM + sub * 8);
                ACC8(r0);
            }
        }
        float inv = deg_inv[node];
        a0 *= inv; a1 *= inv; a2 *= inv; a3 *= inv;
        a4 *= inv; a5 *= inv; a6 *= inv; a7 *= inv;
    }
#undef ACC8

    // pack mean row into swizzled LDS tile
    {
        uint4 o;
        o.x = (u32)f2bf(a0) | ((u32)f2bf(a1) << 16);
        o.y = (u32)f2bf(a2) | ((u32)f2bf(a3) << 16);
        o.z = (u32)f2bf(a4) | ((u32)f2bf(a5) << 16);
        o.w = (u32)f2bf(a6) | ((u32)f2bf(a7) << 16);
        int chunk = sub ^ (nloc & 7);
        *(uint4*)&tile[nloc * 128 + chunk * 8] = o;
    }
    __syncthreads();

    // MFMA phase
    const int fr = sub;
    const int kq = grp << 3;
    bf16x8 aF0[4], aF1[4];
    int rnode = wlid[fr];
    int safe_r = rnode < 0 ? 0 : rnode;
    const u16* ph = h + (size_t)safe_r * DIM + kq;
#pragma unroll
    for (int kt = 0; kt < 4; ++kt) {
        int c = (grp + kt * 4) ^ (fr & 7);
        aF0[kt] = *(const bf16x8*)&tile[fr * 128 + c * 8];
        aF1[kt] = *(const bf16x8*)(ph + kt * 32);
    }
#pragma unroll
    for (int q = 0; q < 2; ++q) {
        int nt = wid * 2 + q;
        const u16* pwl = Wl + (size_t)(nt * 16 + fr) * DIM + kq;
        const u16* pwr = Wr + (size_t)(nt * 16 + fr) * DIM + kq;
        f32x4 acc = {0.f, 0.f, 0.f, 0.f};
#pragma unroll
        for (int kt = 0; kt < 4; ++kt) {
            bf16x8 w = *(const bf16x8*)(pwl + kt * 32);
            acc = __builtin_amdgcn_mfma_f32_16x16x32_bf16(aF0[kt], w, acc, 0, 0, 0);
        }
#pragma unroll
        for (int kt = 0; kt < 4; ++kt) {
            bf16x8 w = *(const bf16x8*)(pwr + kt * 32);
            acc = __builtin_amdgcn_mfma_f32_16x16x32_bf16(aF1[kt], w, acc, 0, 0, 0);
        }
        int col = nt * 16 + fr;
        float b = bias[col];
#pragma unroll
        for (int j = 0; j < 4; ++j) {
            int onode = wlid[(grp << 2) + j];
            if (onode >= 0) {
                float v = acc[j] + b;
                if (RELU) v = fmaxf(v, 0.f);
                out[(size_t)onode * DIM + col] = f2bf(v);
                if (W8) out8[(size_t)onode * DIM + col] = (u8)(pk8<false>(v, v, 0) & 0xffu);
            }
        }
    }
}

// ---------------- head: softmax -> log_softmax -> NLL mean (+finalize) ----------------

__global__ __launch_bounds__(256) void k_head(
    const u16* __restrict__ h3, const int* __restrict__ batch,
    const int* __restrict__ labels, const float* __restrict__ Wlin,
    const float* __restrict__ blin, float* __restrict__ accum,
    int* __restrict__ hcount, float* __restrict__ out) {
    __shared__ float wsh[256];
    __shared__ float red[4];
    int t = threadIdx.x;
    wsh[t] = Wlin[t];
    __syncthreads();

    int lane = t & 63;
    int g    = lane >> 4;
    int sub  = lane & 15;
    int wv   = (blockIdx.x * 256 + t) >> 6;
    int samp = wv * 4 + g;

    float contrib = 0.f;
    float z0 = 0.f, z1 = 0.f;
    int n = 0;
    if (samp < N_BATCH) {
        n = batch[samp];
        uint4 u = *(const uint4*)(h3 + (size_t)n * DIM + sub * 8);
        const u32* uw = (const u32*)&u;
        int cb = sub * 8;
#pragma unroll
        for (int q = 0; q < 4; ++q) {
            float hlo = bf2f((u16)(uw[q] & 0xffffu));
            float hhi = bf2f((u16)(uw[q] >> 16));
            z0 += hlo * wsh[cb + q * 2]       + hhi * wsh[cb + q * 2 + 1];
            z1 += hlo * wsh[128 + cb + q * 2] + hhi * wsh[128 + cb + q * 2 + 1];
        }
    }
#pragma unroll
    for (int off = 8; off > 0; off >>= 1) {
        z0 += __shfl_xor(z0, off);
        z1 += __shfl_xor(z1, off);
    }
    if (samp < N_BATCH) {
        z0 += blin[0]; z1 += blin[1];
        float m  = fmaxf(z0, z1);
        float e0 = expf(z0 - m), e1 = expf(z1 - m);
        float s  = e0 + e1;
        float p0 = e0 / s, p1 = e1 / s;
        float m2  = fmaxf(p0, p1);
        float lse = m2 + logf(expf(p0 - m2) + expf(p1 - m2));
        int lab = labels[n];
        float lp = ((lab == 0) ? p0 : p1) - lse;
        if (sub == 0) contrib = -lp * (1.0f / (float)N_BATCH);
    }
#pragma unroll
    for (int off = 16; off < 64; off <<= 1) contrib += __shfl_xor(contrib, off);
    if (lane == 0) red[t >> 6] = contrib;
    __syncthreads();
    if (t == 0) {
        atomicAdd(accum, red[0] + red[1] + red[2] + red[3]);
        __threadfence();
        int c = atomicAdd(hcount, 1);
        if (c == (int)gridDim.x - 1) {
            float v = atomicAdd(accum, 0.0f);
            out[0] = v;
        }
    }
}

// ---------------- launch ----------------

extern "C" void kernel_launch(void* const* d_in, const int* in_sizes, int n_in,
                              void* d_out, int out_size, void* d_ws, size_t ws_size,
                              hipStream_t stream) {
    const float* x    = (const float*)d_in[0];
    const int*   eidx = (const int*)d_in[1];
    const int*   batch  = (const int*)d_in[2];
    const int*   labels = (const int*)d_in[3];
    const float* W1l = (const float*)d_in[4];
    const float* b1  = (const float*)d_in[5];
    const float* W1r = (const float*)d_in[6];
    const float* W2l = (const float*)d_in[7];
    const float* b2  = (const float*)d_in[8];
    const float* W2r = (const float*)d_in[9];
    const float* W3l = (const float*)d_in[10];
    const float* b3  = (const float*)d_in[11];
    const float* W3r = (const float*)d_in[12];
    const float* Wlin = (const float*)d_in[13];
    const float* blin = (const float*)d_in[14];

    const int* src = eidx;
    const int* dst = eidx + N_EDGES;

    size_t off = 0;
    auto alloc = [&](size_t bytes) -> char* {
        off = (off + 511) & ~(size_t)511;
        char* p = (char*)d_ws + off;
        off += bytes;
        return p;
    };
    // ---- contiguous zero-init region (one hipMemsetAsync) ----
    size_t zbytes = (size_t)MPAD * 4 + NBUCK * 4 + 4 * NBIN * 4 + 8;
    char* zbase = alloc(zbytes);
    int*   mult   = (int*)zbase;
    int*   bcur   = mult + MPAD;
    int*   c1g    = bcur + NBUCK;
    int*   c3g    = c1g + NBIN;
    int*   o1g    = c3g + NBIN;
    int*   o3g    = o1g + NBIN;
    float* accum  = (float*)(o3g + NBIN);
    int*   hcount = (int*)(accum + 1);

    int*   row_ptr = (int*)  alloc(N_NODES * 4);
    int*   deg     = (int*)  alloc(N_NODES * 4);
    float* deg_inv = (float*)alloc(N_NODES * 4);
    int*   csr_src = (int*)  alloc(N_EDGES * 4);
    u64*   ebuf    = (u64*)  alloc((size_t)NBUCK * BCAP * 8);
    u16*   wb      = (u16*)  alloc(6 * DIM * DIM * 2);
    u16*   xb      = (u16*)  alloc((size_t)MPAD * DIM * 2);   // reused as bufB
    u16*   bufA    = (u16*)  alloc((size_t)MPAD * DIM * 2);
    u8*    x8      = (u8*)   alloc((size_t)MPAD * DIM);
    u8*    a8      = (u8*)   alloc((size_t)MPAD * DIM);
    u8*    b8      = (u8*)   alloc((size_t)MPAD * DIM);
    int*   wl1     = (int*)  alloc(MPAD * 4);
    int*   wl3     = (int*)  alloc(MPAD * 4);
    int*   n3      = (int*)  alloc(4);

    u16* bufB = xb;

    u16* w1l = wb + 0 * DIM * DIM;
    u16* w1r = wb + 1 * DIM * DIM;
    u16* w2l = wb + 2 * DIM * DIM;
    u16* w2r = wb + 3 * DIM * DIM;
    u16* w3l = wb + 4 * DIM * DIM;
    u16* w3r = wb + 5 * DIM * DIM;

    const int NB196 = (N_NODES + 255) / 256;      // 196
    const int SGB   = N_NODES / 16;               // 3125
    const int HB2   = (N_BATCH + 15) / 16;        // 1563

    hipMemsetAsync(zbase, 0, zbytes, stream);
    k_setup<<<SB_MK, 256, 0, stream>>>(src, dst, bcur, ebuf,
                                       x, xb, x8,
                                       W1l, W1r, W2l, W2r, W3l, W3r, wb,
                                       batch, mult);
    k_build<<<NBUCK, 256, 0, stream>>>(ebuf, bcur, mult, row_ptr, deg,
                                       deg_inv, csr_src, c1g, c3g);
    k_dscatter<<<NB196, 256, 0, stream>>>(deg, mult, c1g, c3g, o1g, o3g,
                                          wl1, wl3, n3);

    k_sage<true, false, true><<<SGB, 256, 0, stream>>>(
        xb, x8, csr_src, row_ptr, deg, deg_inv, wl1, n3, w1l, w1r, b1, bufA, a8);
    k_sage<true, false, true><<<SGB, 256, 0, stream>>>(
        bufA, a8, csr_src, row_ptr, deg, deg_inv, wl1, n3, w2l, w2r, b2, bufB, b8);
    k_sage<false, true, false><<<SGB, 256, 0, stream>>>(
        bufB, b8, csr_src, row_ptr, deg, deg_inv, wl3, n3, w3l, w3r, b3, bufA, nullptr);

    k_head<<<HB2, 256, 0, stream>>>(bufA, batch, labels, Wlin, blin,
                                    accum, hcount, (float*)d_out);
}

// Round 15
// 190.900 us; speedup vs baseline: 1.1790x; 1.0926x over previous
//
#include <hip/hip_runtime.h>
#include <hip/hip_bf16.h>

#define N_NODES 50000
#define MPAD    50048
#define N_EDGES 800000
#define DIM     128
#define N_BATCH 25000
#define NBUCK   196        // ceil(50000/256) buckets of 256 dst nodes
#define BCAP    8192       // per-bucket capacity (mean 4096, sigma 64)
#define NBIN    64         // degree bins for counting sort

typedef unsigned short u16;
typedef unsigned int   u32;
typedef unsigned char  u8;
typedef unsigned long long u64;

typedef __attribute__((ext_vector_type(8))) short bf16x8;
typedef __attribute__((ext_vector_type(4))) float f32x4;
typedef __attribute__((ext_vector_type(2))) float f32x2;

static __device__ __forceinline__ float bf2f(u16 u) {
    union { u32 i; float f; } v; v.i = ((u32)u) << 16; return v.f;
}
static __device__ __forceinline__ u16 f2bf(float f) {
    union { float f; u32 i; } v; v.f = f;
    u32 x = v.i;
    u32 r = x + 0x7fffu + ((x >> 16) & 1u);   // RTNE
    return (u16)(r >> 16);
}
// pack 2 f32 -> 2 fp8 (e4m3, OCP on gfx950); HI selects dest half (imm required)
template <bool HI>
static __device__ __forceinline__ u32 pk8(float a, float b, u32 old) {
    return (u32)__builtin_amdgcn_cvt_pk_fp8_f32(a, b, (int)old, HI);
}

// ---------------- init: cursors, accumulators, masks, bins ----------------

__global__ void k_init(int* bcur, float* accum, int* hcount, u8* mask,
                       int* c1g, int* c3g, int* o1g, int* o3g) {
    int gid = blockIdx.x * 256 + threadIdx.x;
    if (gid < NBUCK) bcur[gid] = gid * BCAP;
    if (gid < NBIN) { c1g[gid] = 0; c3g[gid] = 0; o1g[gid] = 0; o3g[gid] = 0; }
    if (gid < N_NODES) mask[gid] = 0;
    if (gid == 0) { accum[0] = 0.f; hcount[0] = 0; }
}

// ---- fused setup: edge partition | cast x -> bf16+fp8 | cast W | mark ----

#define SB_PART 196
#define SB_CX   3324
#define SB_CW   3708
#define SB_MK   3806

__global__ __launch_bounds__(256) void k_setup(
    const int* __restrict__ src, const int* __restrict__ dst,
    int* __restrict__ bcur, u64* __restrict__ ebuf,
    const float* __restrict__ x, u16* __restrict__ xb, u8* __restrict__ x8,
    const float* __restrict__ W1l, const float* __restrict__ W1r,
    const float* __restrict__ W2l, const float* __restrict__ W2r,
    const float* __restrict__ W3l, const float* __restrict__ W3r,
    u16* __restrict__ wout,
    const int* __restrict__ batch, u8* __restrict__ mask) {
    __shared__ int hist[NBUCK];
    __shared__ int lbase[NBUCK];
    __shared__ int gdelta[NBUCK];
    __shared__ u64 stage[4096];
    __shared__ int gaddr[4096];
    int bid = blockIdx.x;
    int t = threadIdx.x;

    if (bid < SB_PART) {
        for (int i = t; i < NBUCK; i += 256) hist[i] = 0;
        __syncthreads();

        int base = bid * 4096;
        int cnt = N_EDGES - base; if (cnt > 4096) cnt = 4096; if (cnt < 0) cnt = 0;

        int es[16], ed[16], rr[16];
#pragma unroll
        for (int k = 0; k < 16; ++k) {
            int i = t + (k << 8);
            bool ok = i < cnt;
            int e = ok ? (base + i) : 0;
            int s = src[e], d = dst[e];
            es[k] = s; ed[k] = d;
            int r = -1;
            if (ok) r = atomicAdd(&hist[d >> 8], 1);
            rr[k] = r;
        }
        __syncthreads();

        if (t < 64) {
            int run = 0;
            for (int c = 0; c < 4; ++c) {
                int idx = c * 64 + t;
                int v = (idx < NBUCK) ? hist[idx] : 0;
                int orig = v;
                for (int off = 1; off < 64; off <<= 1) {
                    int u = __shfl_up(v, off);
                    if (t >= off) v += u;
                }
                int tot = __shfl(v, 63);
                if (idx < NBUCK) lbase[idx] = run + v - orig;
                run += tot;
            }
        }
        __syncthreads();

        if (t < NBUCK) {
            int c = hist[t];
            int g = atomicAdd(&bcur[t], c);
            gdelta[t] = g - lbase[t];
        }
        __syncthreads();

#pragma unroll
        for (int k = 0; k < 16; ++k) {
            if (rr[k] >= 0) {
                int b = ed[k] >> 8;
                int slot = lbase[b] + rr[k];
                stage[slot] = (((u64)(u32)ed[k]) << 32) | (u32)es[k];
                gaddr[slot] = gdelta[b] + slot;
            }
        }
        __syncthreads();

        for (int i = t; i < cnt; i += 256) {
            ebuf[gaddr[i]] = stage[i];
        }
    } else if (bid < SB_CX) {
        int gid = (bid - SB_PART) * 256 + t;
        int row = gid >> 4;
        int c8  = (gid & 15) << 3;
        u32 outw[4];
        u32 w0 = 0, w1 = 0;
        if (row < N_NODES) {
            const float4* p = (const float4*)(x + (size_t)row * DIM + c8);
            float4 v0 = p[0], v1 = p[1];
            outw[0] = (u32)f2bf(v0.x) | ((u32)f2bf(v0.y) << 16);
            outw[1] = (u32)f2bf(v0.z) | ((u32)f2bf(v0.w) << 16);
            outw[2] = (u32)f2bf(v1.x) | ((u32)f2bf(v1.y) << 16);
            outw[3] = (u32)f2bf(v1.z) | ((u32)f2bf(v1.w) << 16);
            w0 = pk8<false>(v0.x, v0.y, 0); w0 = pk8<true>(v0.z, v0.w, w0);
            w1 = pk8<false>(v1.x, v1.y, 0); w1 = pk8<true>(v1.z, v1.w, w1);
        } else {
            outw[0] = outw[1] = outw[2] = outw[3] = 0;
        }
        *(uint4*)(xb + (size_t)row * DIM + c8) = *(uint4*)outw;
        uint2 o8; o8.x = w0; o8.y = w1;
        *(uint2*)(x8 + (size_t)row * DIM + c8) = o8;
    } else if (bid < SB_CW) {
        int i = (bid - SB_CX) * 256 + t;
        int mat = i >> 14, off = i & 16383;
        const float* s = (mat == 0) ? W1l : (mat == 1) ? W1r : (mat == 2) ? W2l
                       : (mat == 3) ? W2r : (mat == 4) ? W3l : W3r;
        wout[i] = f2bf(s[off]);
    } else {
        int s = (bid - SB_CW) * 256 + t;
        if (s < N_BATCH) mask[batch[s]] = 1;
    }
}

// ---- per-bucket: self bucket-base scan + degrees + row_ptr + csr + deg hist ----

__global__ __launch_bounds__(256) void k_build(const u64* __restrict__ ebuf,
                                               const int* __restrict__ bcur,
                                               const u8* __restrict__ mask,
                                               int* __restrict__ row_ptr,
                                               int* __restrict__ deg,
                                               float* __restrict__ deg_inv,
                                               int* __restrict__ csr_src,
                                               int* __restrict__ c1g,
                                               int* __restrict__ c3g) {
    __shared__ int cnt256[256];
    __shared__ int sh[256];
    __shared__ int cur[256];
    __shared__ int bh1[NBIN];
    __shared__ int bh3[NBIN];
    __shared__ int shbase;
    int b  = blockIdx.x;
    int t  = threadIdx.x;
    int n0 = b << 8;
    cnt256[t] = 0;
    if (t < NBIN) { bh1[t] = 0; bh3[t] = 0; }
    if (t < 64) {
        int s = 0;
        for (int i = t; i < b; i += 64) s += bcur[i] - i * BCAP;
#pragma unroll
        for (int off = 32; off > 0; off >>= 1) s += __shfl_xor(s, off);
        if (t == 0) shbase = s;
    }
    __syncthreads();
    int bbase = shbase;

    int cnt = bcur[b] - b * BCAP;
    const u64* eb = ebuf + (size_t)b * BCAP;
    for (int i = t; i < cnt; i += 256) {
        int d = (int)(eb[i] >> 32);
        atomicAdd(&cnt256[d - n0], 1);
    }
    __syncthreads();

    int myc = cnt256[t];
    sh[t] = myc;
    __syncthreads();
    for (int off = 1; off < 256; off <<= 1) {
        int x = (t >= off) ? sh[t - off] : 0;
        __syncthreads();
        sh[t] += x;
        __syncthreads();
    }
    int rp = bbase + sh[t] - myc;
    int n  = n0 + t;
    if (n < N_NODES) {
        row_ptr[n] = rp;
        deg[n]     = myc;
        deg_inv[n] = 1.0f / (float)(myc < 1 ? 1 : myc);
        int bin = myc < NBIN ? myc : NBIN - 1;
        atomicAdd(&bh1[bin], 1);
        if (mask[n]) atomicAdd(&bh3[bin], 1);
    }
    cur[t] = rp;
    __syncthreads();

    for (int i = t; i < cnt; i += 256) {
        u64 p = eb[i];
        int d = (int)(p >> 32);
        int s = (int)(u32)p;
        int pos = atomicAdd(&cur[d - n0], 1);
        csr_src[pos] = s;
    }
    __syncthreads();
    if (t < NBIN) {
        if (bh1[t]) atomicAdd(&c1g[t], bh1[t]);
        if (bh3[t]) atomicAdd(&c3g[t], bh3[t]);
    }
}

// ---- counting-sort scatter (self-scanning): nodes into degree-sorted worklists ----

__global__ __launch_bounds__(256) void k_dscatter(const int* __restrict__ deg,
                                                  const u8* __restrict__ mask,
                                                  const int* __restrict__ c1g,
                                                  const int* __restrict__ c3g,
                                                  int* __restrict__ o1g,
                                                  int* __restrict__ o3g,
                                                  int* __restrict__ wl1,
                                                  int* __restrict__ wl3,
                                                  int* __restrict__ n3) {
    __shared__ int bh1[NBIN], bh3[NBIN], bb1[NBIN], bb3[NBIN];
    int t = threadIdx.x;
    int n = blockIdx.x * 256 + t;
    if (t < NBIN) { bh1[t] = 0; bh3[t] = 0; }
    __syncthreads();
    bool valid = n < N_NODES;
    int d = 0, r1 = -1, r3 = -1;
    if (valid) {
        d = deg[n]; if (d >= NBIN) d = NBIN - 1;
        r1 = atomicAdd(&bh1[d], 1);
        if (mask[n]) r3 = atomicAdd(&bh3[d], 1);
    }
    __syncthreads();
    if (t < 64) {
        int v1 = c1g[t], v3 = c3g[t];
        int i1 = v1, i3 = v3;
        for (int off = 1; off < 64; off <<= 1) {
            int u1 = __shfl_up(i1, off);
            int u3 = __shfl_up(i3, off);
            if (t >= off) { i1 += u1; i3 += u3; }
        }
        int res1 = atomicAdd(&o1g[t], bh1[t]);
        int res3 = atomicAdd(&o3g[t], bh3[t]);
        bb1[t] = (i1 - v1) + res1;
        bb3[t] = (i3 - v3) + res3;
        if (blockIdx.x == 0 && t == 63) n3[0] = i3;
    }
    __syncthreads();
    if (valid) {
        wl1[bb1[d] + r1] = n;
        if (r3 >= 0) wl3[bb3[d] + r3] = n;
    }
}

// ---- fused SAGE layer: fp8 gather -> mean -> LDS tile -> MFMA (bf16) ----

template <bool RELU, bool PRUNED, bool W8>
__global__ __launch_bounds__(256) void k_sage(
    const u16* __restrict__ h, const u8* __restrict__ h8,
    const int* __restrict__ csr_src,
    const int* __restrict__ row_ptr, const int* __restrict__ deg,
    const float* __restrict__ deg_inv,
    const int* __restrict__ wl, const int* __restrict__ wlN,
    const u16* __restrict__ Wl, const u16* __restrict__ Wr,
    const float* __restrict__ bias, u16* __restrict__ out,
    u8* __restrict__ out8) {
    __shared__ u16 tile[16 * 128];
    __shared__ int wlid[16];
    int nwl = PRUNED ? wlN[0] : N_NODES;
    int m0  = blockIdx.x * 16;
    if (m0 >= nwl) return;

    int t    = threadIdx.x;
    int lane = t & 63;
    int wid  = t >> 6;
    int sub  = lane & 15;
    int grp  = lane >> 4;
    int nloc = (wid << 2) + grp;
    int gb   = lane & 48;
    int node = (m0 + nloc < nwl) ? wl[m0 + nloc] : -1;
    if (sub == 0) wlid[nloc] = node;

    float a0 = 0, a1 = 0, a2 = 0, a3 = 0, a4 = 0, a5 = 0, a6 = 0, a7 = 0;

#define ACC8(r) { f32x2 p; \
    p = __builtin_amdgcn_cvt_pk_f32_fp8((r).x, false); a0 += p[0]; a1 += p[1]; \
    p = __builtin_amdgcn_cvt_pk_f32_fp8((r).x, true);  a2 += p[0]; a3 += p[1]; \
    p = __builtin_amdgcn_cvt_pk_f32_fp8((r).y, false); a4 += p[0]; a5 += p[1]; \
    p = __builtin_amdgcn_cvt_pk_f32_fp8((r).y, true);  a6 += p[0]; a7 += p[1]; }

    if (node >= 0) {
        int start = row_ptr[node];
        int cnt   = deg[node];
        for (int c0 = 0; c0 < cnt; c0 += 16) {
            int rem = cnt - c0; if (rem > 16) rem = 16;
            int sidx = 0;
            if (sub < rem) sidx = csr_src[start + c0 + sub];
            int j = 0;
            for (; j + 8 <= rem; j += 8) {
                int i0 = __shfl(sidx, gb + j);
                int i1 = __shfl(sidx, gb + j + 1);
                int i2 = __shfl(sidx, gb + j + 2);
                int i3 = __shfl(sidx, gb + j + 3);
                int i4 = __shfl(sidx, gb + j + 4);
                int i5 = __shfl(sidx, gb + j + 5);
                int i6 = __shfl(sidx, gb + j + 6);
                int i7 = __shfl(sidx, gb + j + 7);
                uint2 r0 = *(const uint2*)(h8 + (size_t)i0 * DIM + sub * 8);
                uint2 r1 = *(const uint2*)(h8 + (size_t)i1 * DIM + sub * 8);
                uint2 r2 = *(const uint2*)(h8 + (size_t)i2 * DIM + sub * 8);
                uint2 r3 = *(const uint2*)(h8 + (size_t)i3 * DIM + sub * 8);
                uint2 r4 = *(const uint2*)(h8 + (size_t)i4 * DIM + sub * 8);
                uint2 r5 = *(const uint2*)(h8 + (size_t)i5 * DIM + sub * 8);
                uint2 r6 = *(const uint2*)(h8 + (size_t)i6 * DIM + sub * 8);
                uint2 r7 = *(const uint2*)(h8 + (size_t)i7 * DIM + sub * 8);
                ACC8(r0); ACC8(r1); ACC8(r2); ACC8(r3);
                ACC8(r4); ACC8(r5); ACC8(r6); ACC8(r7);
            }
            for (; j + 4 <= rem; j += 4) {
                int i0 = __shfl(sidx, gb + j);
                int i1 = __shfl(sidx, gb + j + 1);
                int i2 = __shfl(sidx, gb + j + 2);
                int i3 = __shfl(sidx, gb + j + 3);
                uint2 r0 = *(const uint2*)(h8 + (size_t)i0 * DIM + sub * 8);
                uint2 r1 = *(const uint2*)(h8 + (size_t)i1 * DIM + sub * 8);
                uint2 r2 = *(const uint2*)(h8 + (size_t)i2 * DIM + sub * 8);
                uint2 r3 = *(const uint2*)(h8 + (size_t)i3 * DIM + sub * 8);
                ACC8(r0); ACC8(r1); ACC8(r2); ACC8(r3);
            }
            for (; j < rem; ++j) {
                int i0 = __shfl(sidx, gb + j);
                uint2 r0 = *(const uint2*)(h8 + (size_t)i0 * DIM + sub * 8);
                ACC8(r0);
            }
        }
        float inv = deg_inv[node];
        a0 *= inv; a1 *= inv; a2 *= inv; a3 *= inv;
        a4 *= inv; a5 *= inv; a6 *= inv; a7 *= inv;
    }
#undef ACC8

    // pack mean row into swizzled LDS tile
    {
        uint4 o;
        o.x = (u32)f2bf(a0) | ((u32)f2bf(a1) << 16);
        o.y = (u32)f2bf(a2) | ((u32)f2bf(a3) << 16);
        o.z = (u32)f2bf(a4) | ((u32)f2bf(a5) << 16);
        o.w = (u32)f2bf(a6) | ((u32)f2bf(a7) << 16);
        int chunk = sub ^ (nloc & 7);
        *(uint4*)&tile[nloc * 128 + chunk * 8] = o;
    }
    __syncthreads();

    // MFMA phase
    const int fr = sub;
    const int kq = grp << 3;
    bf16x8 aF0[4], aF1[4];
    int rnode = wlid[fr];
    int safe_r = rnode < 0 ? 0 : rnode;
    const u16* ph = h + (size_t)safe_r * DIM + kq;
#pragma unroll
    for (int kt = 0; kt < 4; ++kt) {
        int c = (grp + kt * 4) ^ (fr & 7);
        aF0[kt] = *(const bf16x8*)&tile[fr * 128 + c * 8];
        aF1[kt] = *(const bf16x8*)(ph + kt * 32);
    }
#pragma unroll
    for (int q = 0; q < 2; ++q) {
        int nt = wid * 2 + q;
        const u16* pwl = Wl + (size_t)(nt * 16 + fr) * DIM + kq;
        const u16* pwr = Wr + (size_t)(nt * 16 + fr) * DIM + kq;
        f32x4 acc = {0.f, 0.f, 0.f, 0.f};
#pragma unroll
        for (int kt = 0; kt < 4; ++kt) {
            bf16x8 w = *(const bf16x8*)(pwl + kt * 32);
            acc = __builtin_amdgcn_mfma_f32_16x16x32_bf16(aF0[kt], w, acc, 0, 0, 0);
        }
#pragma unroll
        for (int kt = 0; kt < 4; ++kt) {
            bf16x8 w = *(const bf16x8*)(pwr + kt * 32);
            acc = __builtin_amdgcn_mfma_f32_16x16x32_bf16(aF1[kt], w, acc, 0, 0, 0);
        }
        int col = nt * 16 + fr;
        float b = bias[col];
#pragma unroll
        for (int j = 0; j < 4; ++j) {
            int onode = wlid[(grp << 2) + j];
            if (onode >= 0) {
                float v = acc[j] + b;
                if (RELU) v = fmaxf(v, 0.f);
                out[(size_t)onode * DIM + col] = f2bf(v);
                if (W8) out8[(size_t)onode * DIM + col] = (u8)(pk8<false>(v, v, 0) & 0xffu);
            }
        }
    }
}

// ---------------- head: softmax -> log_softmax -> NLL mean (+finalize) ----------------

__global__ __launch_bounds__(256) void k_head(
    const u16* __restrict__ h3, const int* __restrict__ batch,
    const int* __restrict__ labels, const float* __restrict__ Wlin,
    const float* __restrict__ blin, float* __restrict__ accum,
    int* __restrict__ hcount, float* __restrict__ out) {
    __shared__ float wsh[256];
    __shared__ float red[4];
    int t = threadIdx.x;
    wsh[t] = Wlin[t];
    __syncthreads();

    int lane = t & 63;
    int g    = lane >> 4;
    int sub  = lane & 15;
    int wv   = (blockIdx.x * 256 + t) >> 6;
    int samp = wv * 4 + g;

    float contrib = 0.f;
    float z0 = 0.f, z1 = 0.f;
    int n = 0;
    if (samp < N_BATCH) {
        n = batch[samp];
        uint4 u = *(const uint4*)(h3 + (size_t)n * DIM + sub * 8);
        const u32* uw = (const u32*)&u;
        int cb = sub * 8;
#pragma unroll
        for (int q = 0; q < 4; ++q) {
            float hlo = bf2f((u16)(uw[q] & 0xffffu));
            float hhi = bf2f((u16)(uw[q] >> 16));
            z0 += hlo * wsh[cb + q * 2]       + hhi * wsh[cb + q * 2 + 1];
            z1 += hlo * wsh[128 + cb + q * 2] + hhi * wsh[128 + cb + q * 2 + 1];
        }
    }
#pragma unroll
    for (int off = 8; off > 0; off >>= 1) {
        z0 += __shfl_xor(z0, off);
        z1 += __shfl_xor(z1, off);
    }
    if (samp < N_BATCH) {
        z0 += blin[0]; z1 += blin[1];
        float m  = fmaxf(z0, z1);
        float e0 = expf(z0 - m), e1 = expf(z1 - m);
        float s  = e0 + e1;
        float p0 = e0 / s, p1 = e1 / s;
        float m2  = fmaxf(p0, p1);
        float lse = m2 + logf(expf(p0 - m2) + expf(p1 - m2));
        int lab = labels[n];
        float lp = ((lab == 0) ? p0 : p1) - lse;
        if (sub == 0) contrib = -lp * (1.0f / (float)N_BATCH);
    }
#pragma unroll
    for (int off = 16; off < 64; off <<= 1) contrib += __shfl_xor(contrib, off);
    if (lane == 0) red[t >> 6] = contrib;
    __syncthreads();
    if (t == 0) {
        atomicAdd(accum, red[0] + red[1] + red[2] + red[3]);
        __threadfence();
        int c = atomicAdd(hcount, 1);
        if (c == (int)gridDim.x - 1) {
            float v = atomicAdd(accum, 0.0f);
            out[0] = v;
        }
    }
}

// ---------------- launch ----------------

extern "C" void kernel_launch(void* const* d_in, const int* in_sizes, int n_in,
                              void* d_out, int out_size, void* d_ws, size_t ws_size,
                              hipStream_t stream) {
    const float* x    = (const float*)d_in[0];
    const int*   eidx = (const int*)d_in[1];
    const int*   batch  = (const int*)d_in[2];
    const int*   labels = (const int*)d_in[3];
    const float* W1l = (const float*)d_in[4];
    const float* b1  = (const float*)d_in[5];
    const float* W1r = (const float*)d_in[6];
    const float* W2l = (const float*)d_in[7];
    const float* b2  = (const float*)d_in[8];
    const float* W2r = (const float*)d_in[9];
    const float* W3l = (const float*)d_in[10];
    const float* b3  = (const float*)d_in[11];
    const float* W3r = (const float*)d_in[12];
    const float* Wlin = (const float*)d_in[13];
    const float* blin = (const float*)d_in[14];

    const int* src = eidx;
    const int* dst = eidx + N_EDGES;

    size_t off = 0;
    auto alloc = [&](size_t bytes) -> char* {
        off = (off + 511) & ~(size_t)511;
        char* p = (char*)d_ws + off;
        off += bytes;
        return p;
    };
    int*   bcur    = (int*)  alloc(NBUCK * 4);
    int*   row_ptr = (int*)  alloc(N_NODES * 4);
    int*   deg     = (int*)  alloc(N_NODES * 4);
    float* deg_inv = (float*)alloc(N_NODES * 4);
    int*   csr_src = (int*)  alloc(N_EDGES * 4);
    u64*   ebuf    = (u64*)  alloc((size_t)NBUCK * BCAP * 8);
    u16*   wb      = (u16*)  alloc(6 * DIM * DIM * 2);
    u16*   xb      = (u16*)  alloc((size_t)MPAD * DIM * 2);   // reused as bufB
    u16*   bufA    = (u16*)  alloc((size_t)MPAD * DIM * 2);
    u8*    x8      = (u8*)   alloc((size_t)MPAD * DIM);
    u8*    a8      = (u8*)   alloc((size_t)MPAD * DIM);
    u8*    b8      = (u8*)   alloc((size_t)MPAD * DIM);
    u8*    mask    = (u8*)   alloc(N_NODES);
    int*   c1g     = (int*)  alloc(NBIN * 4);
    int*   c3g     = (int*)  alloc(NBIN * 4);
    int*   o1g     = (int*)  alloc(NBIN * 4);
    int*   o3g     = (int*)  alloc(NBIN * 4);
    int*   wl1     = (int*)  alloc(MPAD * 4);
    int*   wl3     = (int*)  alloc(MPAD * 4);
    int*   n3      = (int*)  alloc(4);
    float* accum   = (float*)alloc(4);
    int*   hcount  = (int*)  alloc(4);

    u16* bufB = xb;

    u16* w1l = wb + 0 * DIM * DIM;
    u16* w1r = wb + 1 * DIM * DIM;
    u16* w2l = wb + 2 * DIM * DIM;
    u16* w2r = wb + 3 * DIM * DIM;
    u16* w3l = wb + 4 * DIM * DIM;
    u16* w3r = wb + 5 * DIM * DIM;

    const int NB196 = (N_NODES + 255) / 256;      // 196
    const int SGB   = N_NODES / 16;               // 3125
    const int HB2   = (N_BATCH + 15) / 16;        // 1563

    k_init<<<NB196, 256, 0, stream>>>(bcur, accum, hcount, mask, c1g, c3g, o1g, o3g);
    k_setup<<<SB_MK, 256, 0, stream>>>(src, dst, bcur, ebuf,
                                       x, xb, x8,
                                       W1l, W1r, W2l, W2r, W3l, W3r, wb,
                                       batch, mask);
    k_build<<<NBUCK, 256, 0, stream>>>(ebuf, bcur, mask, row_ptr, deg,
                                       deg_inv, csr_src, c1g, c3g);
    k_dscatter<<<NB196, 256, 0, stream>>>(deg, mask, c1g, c3g, o1g, o3g,
                                          wl1, wl3, n3);

    k_sage<true, false, true><<<SGB, 256, 0, stream>>>(
        xb, x8, csr_src, row_ptr, deg, deg_inv, wl1, n3, w1l, w1r, b1, bufA, a8);
    k_sage<true, false, true><<<SGB, 256, 0, stream>>>(
        bufA, a8, csr_src, row_ptr, deg, deg_inv, wl1, n3, w2l, w2r, b2, bufB, b8);
    k_sage<false, true, false><<<SGB, 256, 0, stream>>>(
        bufB, b8, csr_src, row_ptr, deg, deg_inv, wl3, n3, w3l, w3r, b3, bufA, nullptr);

    k_head<<<HB2, 256, 0, stream>>>(bufA, batch, labels, Wlin, blin,
                                    accum, hcount, (float*)d_out);
}